// Round 11
// baseline (386.652 us; speedup 1.0000x reference)
//
#include <hip/hip_runtime.h>
#include <hip/hip_bf16.h>
#include <stdint.h>

#define EPSF 1e-5f

typedef __attribute__((ext_vector_type(8))) short short8;
typedef __attribute__((ext_vector_type(4))) float f32x4;

__device__ inline short f2bf(float f) {
    union { float f; unsigned u; } x; x.f = f;
    unsigned u = x.u;
    unsigned r = (u + 0x7FFFu + ((u >> 16) & 1u)) >> 16;  // round-to-nearest-even
    return (short)r;
}

__device__ inline f32x4 mfma16x16x32(short8 a, short8 b, f32x4 c) {
    return __builtin_amdgcn_mfma_f32_16x16x32_bf16(a, b, c, 0, 0, 0);
}

// K-tile-major blocked layouts for the big fc GEMM. K = 96*392 = 37632 EXACT
// (1176 tiles of 32).  flat2[ks][b][32] (A)   fcw2[ks][d in 512][32] (B).
// 16B block jb stored at jb ^ ((row>>1)&3): bank swizzle baked into memory.

// ---------------------------------------------------------------------------
// fck80: C_part[z] = A2 * W2^T slice, N = 400 EXACT (no padding waste).
// Block 256x80, grid (8,5,13). 4 waves stacked in M: wave tile 64x80
// (4 mi x 5 ni frags, 20 MFMA/step). A: 4-slab LDS, each wave stages AND
// reads ONLY its own 64 rows -> ZERO barriers in the K-loop; waves free-run.
// A staged t+3 ahead; B (5 frags) in registers 1-ahead (compiler auto-waits
// the register dependency). Manual A-visibility wait = #VM-ops issued after
// A(t)'s stage batch, derived exactly:
//   prologue order: B(0)[5], A(0)[4], A(1)[4], A(2)[4]
//   step s issues:  B(s+1)[5] (if s+1<nt), A(s+3)[4] (if s+3<nt), then wait
//   t=0 -> 17, t=1 -> 22, steady -> 27, tail rem=2/1/0 -> 23/19/10
// ---------------------------------------------------------------------------
__global__ __launch_bounds__(256, 2) void gemm_fck80(
    const short* __restrict__ A2, const short* __restrict__ W2,
    float* __restrict__ C, int CHUNK)
{
    __shared__ alignas(16) short As[4][256 * 32];

    const int tid = threadIdx.x;
    const int l   = tid & 63;
    const int w   = tid >> 6;          // wave 0..3, owns rows w*64..w*64+63
    const int m0  = blockIdx.x * 256;
    const int nb  = blockIdx.y * 80;

    const int TILES = 1176;
    long long z = blockIdx.z;
    const int s0 = (int)(z * TILES / gridDim.z);
    const int s1 = (int)((z + 1) * TILES / gridDim.z);
    const int nt = s1 - s0;

    const int lr   = l & 15;
    const int kg   = l >> 4;
    const int kswz = (kg ^ ((lr >> 1) & 3)) * 8;

    const size_t ASTEP = (size_t)CHUNK * 32;
    const size_t BSTEP = 512 * 32;
    const short* aB = A2 + (size_t)s0 * ASTEP + (size_t)m0 * 32 + w * 2048 + l * 8;
    const short* bP[5];
#pragma unroll
    for (int ni = 0; ni < 5; ++ni)
        bP[ni] = W2 + (size_t)s0 * BSTEP + (size_t)(nb + ni * 16 + lr) * 32 + kswz;

    auto stageA = [&](int buf, int tk) {
        const short* p = aB + (size_t)tk * ASTEP;
#pragma unroll
        for (int i = 0; i < 4; ++i)
            __builtin_amdgcn_global_load_lds(
                (const __attribute__((address_space(1))) void*)(p + i * 512),
                (__attribute__((address_space(3))) void*)(&As[buf][(w * 4 + i) * 512]), 16, 0, 0);
    };

    f32x4 acc[4][5] = {};
    short8 bC[5], bN[5];
    int rd = 0;

    // prologue: B(0) first, then A(0..2)  (order matters for the wait ladder)
#pragma unroll
    for (int ni = 0; ni < 5; ++ni) bC[ni] = *(const short8*)(bP[ni]);
    stageA(0, 0);
    if (nt > 1) stageA(1, 1);
    if (nt > 2) stageA(2, 2);

    auto kstep = [&](int t, const short8 (&u)[5], short8 (&v)[5]) {
        if (t + 1 < nt) {
            const size_t bo = (size_t)(t + 1) * BSTEP;
#pragma unroll
            for (int ni = 0; ni < 5; ++ni) v[ni] = *(const short8*)(bP[ni] + bo);
        }
        if (t + 3 < nt) {
            int wb = rd + 3; if (wb >= 4) wb -= 4;
            stageA(wb, t + 3);
        }
        // A(t) visibility ladder (see header derivation)
        const int rem = nt - 1 - t;
        if (t == 0)          { asm volatile("s_waitcnt vmcnt(17)" ::: "memory"); }
        else if (t == 1)     { asm volatile("s_waitcnt vmcnt(22)" ::: "memory"); }
        else if (rem >= 3)   { asm volatile("s_waitcnt vmcnt(27)" ::: "memory"); }
        else if (rem == 2)   { asm volatile("s_waitcnt vmcnt(23)" ::: "memory"); }
        else if (rem == 1)   { asm volatile("s_waitcnt vmcnt(19)" ::: "memory"); }
        else                 { asm volatile("s_waitcnt vmcnt(10)" ::: "memory"); }
        const short* Ar = &As[rd][0];
        short8 af[4];
#pragma unroll
        for (int mi = 0; mi < 4; ++mi)
            af[mi] = *(const short8*)&Ar[(w * 64 + mi * 16 + lr) * 32 + kswz];
        asm volatile("s_waitcnt lgkmcnt(0)" ::: "memory");
        __builtin_amdgcn_sched_barrier(0);
        __builtin_amdgcn_s_setprio(1);
#pragma unroll
        for (int mi = 0; mi < 4; ++mi)
#pragma unroll
            for (int ni = 0; ni < 5; ++ni)
                acc[mi][ni] = mfma16x16x32(af[mi], u[ni], acc[mi][ni]);
        __builtin_amdgcn_s_setprio(0);
        __builtin_amdgcn_sched_barrier(0);
        if (++rd == 4) rd = 0;
    };

    int t = 0;
    for (; t + 2 <= nt; t += 2) {
        kstep(t,     bC, bN);
        kstep(t + 1, bN, bC);
    }
    if (t < nt) kstep(t, bC, bN);

    float* Cb = C + (size_t)z * CHUNK * 400;
#pragma unroll
    for (int ni = 0; ni < 5; ++ni) {
        int col = nb + ni * 16 + lr;
#pragma unroll
        for (int mi = 0; mi < 4; ++mi) {
            int row0 = m0 + w * 64 + mi * 16 + kg * 4;
#pragma unroll
            for (int r = 0; r < 4; ++r)
                Cb[(size_t)(row0 + r) * 400 + col] = acc[mi][ni][r];
        }
    }
}

// ---------------------------------------------------------------------------
// BT-GEMM template (round-7 structure): row-major A[M,KP], B[N,KP], full-K
// + bias. MF = mi-frags/wave: block = (MF*32) x 128. MF=8: 72KB LDS, 2/CU.
// MF=4: 48KB LDS, 3/CU (for short-K GEMMs needing more blocks: fc1, logits).
// ---------------------------------------------------------------------------
template <int MF>
__global__ __launch_bounds__(256, 2) void gemm_bt(
    const short* __restrict__ A, const short* __restrict__ B,
    float* __restrict__ C, int M, int N, int KP, int ldc,
    const float* __restrict__ bias)
{
    constexpr int RM = MF * 32;           // block rows
    constexpr int HG = MF / 2;            // A groups staged per wave
    __shared__ alignas(16) short As[3][RM * 32];
    __shared__ alignas(16) short Bs[3][128 * 32];

    const int tid = threadIdx.x;
    const int l   = tid & 63;
    const int w   = tid >> 6;
    const int wr  = w >> 1, wc = w & 1;
    const int m0  = blockIdx.x * RM;
    const int n0  = blockIdx.y * 128;

    const int sr   = l >> 2;
    const int sc   = ((l & 3) ^ ((sr >> 1) & 3)) * 8;
    const int lr   = l & 15;
    const int kg   = l >> 4;
    const int kswz = (kg ^ ((lr >> 1) & 3)) * 8;

    const short* gaB[HG];
#pragma unroll
    for (int i = 0; i < HG; ++i)
        gaB[i] = A + (size_t)(m0 + (w * HG + i) * 16 + sr) * KP + sc;
    const short* gbB[2];
#pragma unroll
    for (int i = 0; i < 2; ++i) {
        int rB = n0 + (w * 2 + i) * 16 + sr;
        if (rB > N - 1) rB = N - 1;
        gbB[i] = B + (size_t)rB * KP + sc;
    }

    auto stageA = [&](int buf, int k0) {
#pragma unroll
        for (int i = 0; i < HG; ++i)
            __builtin_amdgcn_global_load_lds(
                (const __attribute__((address_space(1))) void*)(gaB[i] + k0),
                (__attribute__((address_space(3))) void*)(&As[buf][(w * HG + i) * 512]), 16, 0, 0);
    };
    auto stageB = [&](int buf, int k0) {
#pragma unroll
        for (int i = 0; i < 2; ++i)
            __builtin_amdgcn_global_load_lds(
                (const __attribute__((address_space(1))) void*)(gbB[i] + k0),
                (__attribute__((address_space(3))) void*)(&Bs[buf][(w * 2 + i) * 512]), 16, 0, 0);
    };
    auto wait_batch = [&]() {   // keep one stage batch (HG+2 ops) in flight
        if constexpr (MF == 8) { asm volatile("s_waitcnt vmcnt(6)" ::: "memory"); }
        else                   { asm volatile("s_waitcnt vmcnt(4)" ::: "memory"); }
    };

    f32x4 acc[MF][4] = {};

    const int nt = KP >> 5;
    stageA(0, 0); stageB(0, 0);
    if (nt > 1) { stageA(1, 32); stageB(1, 32); }
    if (nt > 1) { wait_batch(); }
    else        { asm volatile("s_waitcnt vmcnt(0)" ::: "memory"); }
    __builtin_amdgcn_s_barrier();
    __builtin_amdgcn_sched_barrier(0);

    int rd = 0;
    for (int t = 0; t < nt; ++t) {
        int wb = rd + 2; if (wb >= 3) wb -= 3;
        const int kpre = (t + 2) << 5;
        const short* Ar = &As[rd][0];
        const short* Br = &Bs[rd][0];
        short8 af[HG], bf[4], af2[HG];

#pragma unroll
        for (int mi = 0; mi < HG; ++mi)
            af[mi] = *(const short8*)&Ar[(wr * (MF * 16) + mi * 16 + lr) * 32 + kswz];
#pragma unroll
        for (int ni = 0; ni < 4; ++ni)
            bf[ni] = *(const short8*)&Br[(wc * 64 + ni * 16 + lr) * 32 + kswz];
        if (t + 2 < nt) stageA(wb, kpre);
        __builtin_amdgcn_s_barrier();
        asm volatile("s_waitcnt lgkmcnt(0)" ::: "memory");
        __builtin_amdgcn_sched_barrier(0);
        __builtin_amdgcn_s_setprio(1);
#pragma unroll
        for (int mi = 0; mi < HG; ++mi)
#pragma unroll
            for (int ni = 0; ni < 4; ++ni)
                acc[mi][ni] = mfma16x16x32(af[mi], bf[ni], acc[mi][ni]);
        __builtin_amdgcn_s_setprio(0);
        __builtin_amdgcn_sched_barrier(0);
        __builtin_amdgcn_s_barrier();
        __builtin_amdgcn_sched_barrier(0);

#pragma unroll
        for (int mi = 0; mi < HG; ++mi)
            af2[mi] = *(const short8*)&Ar[(wr * (MF * 16) + (mi + HG) * 16 + lr) * 32 + kswz];
        if (t + 2 < nt) stageB(wb, kpre);
        __builtin_amdgcn_s_barrier();
        asm volatile("s_waitcnt lgkmcnt(0)" ::: "memory");
        __builtin_amdgcn_sched_barrier(0);
        __builtin_amdgcn_s_setprio(1);
#pragma unroll
        for (int mi = 0; mi < HG; ++mi)
#pragma unroll
            for (int ni = 0; ni < 4; ++ni)
                acc[mi + HG][ni] = mfma16x16x32(af2[mi], bf[ni], acc[mi + HG][ni]);
        __builtin_amdgcn_s_setprio(0);
        __builtin_amdgcn_sched_barrier(0);
        if (t + 2 < nt) { wait_batch(); }
        else            { asm volatile("s_waitcnt vmcnt(0)" ::: "memory"); }
        __builtin_amdgcn_s_barrier();
        __builtin_amdgcn_sched_barrier(0);

        if (++rd == 3) rd = 0;
    }

#pragma unroll
    for (int ni = 0; ni < 4; ++ni) {
        int col = n0 + wc * 64 + ni * 16 + lr;
        if (col >= N) continue;
        float bv = bias ? bias[col] : 0.0f;
#pragma unroll
        for (int mi = 0; mi < MF; ++mi) {
            int row0 = m0 + wr * (MF * 16) + mi * 16 + kg * 4;
#pragma unroll
            for (int r = 0; r < 4; ++r)
                C[(size_t)(row0 + r) * ldc + col] = acc[mi][ni][r] + bv;
        }
    }
}

// ---------------------------------------------------------------------------
// fused gathers: entity row + BN0 -> f32 x[2048,400]; relation row -> bf16
// padded to 416 cols
// ---------------------------------------------------------------------------
__global__ void gather_fused(const float* __restrict__ E, const int* __restrict__ eidx,
                             const float* __restrict__ R, const int* __restrict__ ridx,
                             const float* g, const float* bb, const float* m,
                             const float* v, float* __restrict__ xout,
                             short* __restrict__ rout)
{
    int b = blockIdx.x;
    int e = eidx[b];
    float s = g[0] * rsqrtf(v[0] + EPSF);
    float t = bb[0] - m[0] * s;
    const float4* src = (const float4*)(E + (size_t)e * 400);
    float4* dst = (float4*)(xout + (size_t)b * 400);
    for (int i = threadIdx.x; i < 100; i += blockDim.x) {
        float4 u = src[i];
        dst[i] = make_float4(u.x * s + t, u.y * s + t, u.z * s + t, u.w * s + t);
    }
    int r = ridx[b];
    const float* rsrc = R + (size_t)r * 400;
    short* rdst = rout + (size_t)b * 416;
    for (int i = threadIdx.x; i < 416; i += blockDim.x)
        rdst[i] = (i < 400) ? f2bf(rsrc[i]) : (short)0;
}

// fc_w (400 x 37632) f32 -> blocked/swizzled fcw2[ks][512][32] bf16.
__global__ void cvt_fcw2(const float* __restrict__ fc_w, short* __restrict__ fcw2)
{
    int i = blockIdx.x * blockDim.x + threadIdx.x;
    if (i >= 1176 * 512 * 4) return;
    int p  = i & 3;
    int d  = (i >> 2) & 511;
    int ks = i >> 11;
    int jb = p ^ ((d >> 1) & 3);
    int c0 = ks * 32 + jb * 8;
    unsigned o = (unsigned)c0 / 392u;
    int lc = c0 - (int)o * 392;
    short8 v = {};
    if (d < 400) {
        const float* src = fc_w + (size_t)d * 37632 + o * 392 + lc;
#pragma unroll
        for (int j = 0; j < 8; ++j) v[j] = f2bf(src[j]);
    }
    *(short8*)(fcw2 + (size_t)i * 8) = v;
}

// fc1_w (864 x 400) f32 -> bf16 padded to ld 416
__global__ void cvt_fc1w_pad(const float* __restrict__ in, short* __restrict__ out)
{
    int i = blockIdx.x * blockDim.x + threadIdx.x;
    if (i >= 864 * 416) return;
    int row = i / 416, col = i - row * 416;
    out[i] = (col < 400) ? f2bf(in[row * 400 + col]) : (short)0;
}

// ---------------------------------------------------------------------------
// conv + BN1 -> blocked/swizzled flat2[ks][rc][32] bf16 (round-10 verified).
// ---------------------------------------------------------------------------
__global__ __launch_bounds__(256, 3) void conv_blk(
    const float* __restrict__ xall, const float* __restrict__ kfall,
    const float* __restrict__ g1, const float* __restrict__ b1,
    const float* __restrict__ m1, const float* __restrict__ v1,
    short* __restrict__ flat2, int CHUNK, int cb)
{
    __shared__ float xs[8][401];
    __shared__ float kfs[8][866];
    __shared__ float s1s[96], t1s[96];

    const int tid = threadIdx.x;
    const int b0  = blockIdx.x * 8;
    const int ts0 = blockIdx.y * 588;
    const int ts1 = ts0 + 588;

    for (int i = tid; i < 800; i += 256) {
        int row = i / 100, q = i - row * 100;
        float4 u = ((const float4*)(xall + (size_t)(cb + b0 + row) * 400))[q];
        xs[row][q * 4 + 0] = u.x; xs[row][q * 4 + 1] = u.y;
        xs[row][q * 4 + 2] = u.z; xs[row][q * 4 + 3] = u.w;
    }
    for (int i = tid; i < 1728; i += 256) {
        int row = i / 216, q = i - row * 216;
        float4 u = ((const float4*)(kfall + (size_t)(cb + b0 + row) * 864))[q];
        kfs[row][q * 4 + 0] = u.x; kfs[row][q * 4 + 1] = u.y;
        kfs[row][q * 4 + 2] = u.z; kfs[row][q * 4 + 3] = u.w;
    }
    if (tid < 96) {
        float s = g1[tid] * rsqrtf(v1[tid] + EPSF);
        s1s[tid] = s;
        t1s[tid] = b1[tid] - m1[tid] * s;
    }
    __syncthreads();

    const int l  = tid & 63;
    const int w  = tid >> 6;
    const int th = l >> 5;
    const int sl = (l >> 2) & 7;
    const int p  = l & 3;
    const int rc = b0 + sl;
    const int jb = p ^ ((rc >> 1) & 3);

    const float* xr = &xs[sl][0];
    const float* kr = &kfs[sl][0];
    short* outb = flat2 + (size_t)rc * 32 + p * 8;

    for (int ks = ts0 + w * 2 + th; ks < ts1; ks += 8) {
        int c0 = ks * 32 + jb * 8;
        unsigned o = (unsigned)c0 / 392u;
        int l0 = c0 - (int)o * 392;
        float k9[9];
#pragma unroll
        for (int f = 0; f < 9; ++f) k9[f] = kr[o * 9 + f];
        float s1 = s1s[o], t1 = t1s[o];
        float xv[16];
#pragma unroll
        for (int j = 0; j < 16; ++j) xv[j] = xr[l0 + j];
        short8 v;
#pragma unroll
        for (int j = 0; j < 8; ++j) {
            float a = 0.f;
#pragma unroll
            for (int f = 0; f < 9; ++f) a += xv[j + f] * k9[f];
            v[j] = f2bf(a * s1 + t1);
        }
        *(short8*)(outb + (size_t)ks * CHUNK * 32) = v;
    }
}

// sum NZ split-K partials + fc_b + BN2 + ReLU -> bf16 x_out rows, ld 416 (pad=0)
__global__ void reduce_bn2(const float* __restrict__ hp, int C, int nz,
                           const float* __restrict__ fcb,
                           const float* __restrict__ g2, const float* __restrict__ b2,
                           const float* __restrict__ m2, const float* __restrict__ v2,
                           short* __restrict__ xout, int cb)
{
    int i = blockIdx.x * blockDim.x + threadIdx.x;
    int total = C * 416;
    if (i >= total) return;
    int row = i / 416, col = i - row * 416;
    short val = 0;
    if (col < 400) {
        float s = 0.f;
        size_t stride = (size_t)C * 400;
        size_t basei = (size_t)row * 400 + col;
        for (int k = 0; k < nz; ++k) s += hp[k * stride + basei];
        float sc = g2[col] * rsqrtf(v2[col] + EPSF);
        float hv = (s + fcb[col] - m2[col]) * sc + b2[col];
        val = f2bf(fmaxf(hv, 0.f));
    }
    xout[(size_t)(cb + row) * 416 + col] = val;
}

extern "C" void kernel_launch(void* const* d_in, const int* in_sizes, int n_in,
                              void* d_out, int out_size, void* d_ws, size_t ws_size,
                              hipStream_t stream)
{
    (void)in_sizes; (void)n_in; (void)out_size;
    const int*   e1    = (const int*)d_in[0];
    const int*   r1i   = (const int*)d_in[1];
    const int*   r2i   = (const int*)d_in[2];
    const int*   e2    = (const int*)d_in[3];
    const float* E_w   = (const float*)d_in[4];
    const float* R_w   = (const float*)d_in[5];
    const float* fc1_w = (const float*)d_in[6];
    const float* fc1_b = (const float*)d_in[7];
    const float* fc_w  = (const float*)d_in[8];
    const float* fc_b  = (const float*)d_in[9];
    const float* bn0_g = (const float*)d_in[10];
    const float* bn0_b = (const float*)d_in[11];
    const float* bn0_m = (const float*)d_in[12];
    const float* bn0_v = (const float*)d_in[13];
    const float* bn1_g = (const float*)d_in[14];
    const float* bn1_b = (const float*)d_in[15];
    const float* bn1_m = (const float*)d_in[16];
    const float* bn1_v = (const float*)d_in[17];
    const float* bn2_g = (const float*)d_in[18];
    const float* bn2_b = (const float*)d_in[19];
    const float* bn2_m = (const float*)d_in[20];
    const float* bn2_v = (const float*)d_in[21];
    const float* bbias = (const float*)d_in[22];
    float* out = (float*)d_out;

    char* basep = (char*)d_ws;
    size_t off = 0;
    auto alloc = [&](size_t bytes) -> char* {
        char* p = basep + off;
        off = (off + bytes + 255) & ~(size_t)255;
        return p;
    };
    short* fcw2   = (short*)alloc(1176ULL * 512 * 32 * 2);
    short* fc1w_b = (short*)alloc(864ULL * 416 * 2);
    float* xf     = (float*)alloc(2048ULL * 400 * 4);
    short* rb     = (short*)alloc(2048ULL * 416 * 2);
    float* kf     = (float*)alloc(2048ULL * 864 * 4);
    short* x1b    = (short*)alloc(2048ULL * 416 * 2);
    short* x2b    = (short*)alloc(2048ULL * 416 * 2);
    size_t fixed = off;

    const int NZ = 13;   // split-K ways: grid 8x5x13 = 520 ~ 2 blocks/CU
    int CHUNK = 256;
    for (int c = 2048; c >= 256; c >>= 1) {
        size_t need = fixed + ((size_t)c * 400 * NZ * 4 + 256)
                            + ((size_t)c * 37632 * 2 + 256);
        if (need <= ws_size) { CHUNK = c; break; }
    }
    float* hpart = (float*)alloc((size_t)CHUNK * 400 * NZ * 4);
    short* flat2 = (short*)alloc((size_t)CHUNK * 37632 * 2);

    cvt_fcw2<<<(1176 * 512 * 4 + 255) / 256, 256, 0, stream>>>(fc_w, fcw2);
    cvt_fc1w_pad<<<(864 * 416 + 255) / 256, 256, 0, stream>>>(fc1_w, fc1w_b);

    for (int br = 0; br < 2; ++br) {
        const int* eidx = (br == 0) ? e1 : e2;
        const int* ridx = (br == 0) ? r1i : r2i;
        short* xob = (br == 0) ? x1b : x2b;

        gather_fused<<<2048, 128, 0, stream>>>(E_w, eidx, R_w, ridx,
                                               bn0_g, bn0_b, bn0_m, bn0_v, xf, rb);
        // k filters: (2048x400) @ (864x400)^T + fc1_b -> f32 (2048x864)
        gemm_bt<4><<<dim3(16, 7), 256, 0, stream>>>(rb, fc1w_b, kf, 2048, 864, 416, 864, fc1_b);

        for (int cb = 0; cb < 2048; cb += CHUNK) {
            conv_blk<<<dim3(CHUNK / 8, 2), 256, 0, stream>>>(
                xf, kf, bn1_g, bn1_b, bn1_m, bn1_v, flat2, CHUNK, cb);
            gemm_fck80<<<dim3(CHUNK / 256, 5, NZ), 256, 0, stream>>>(
                flat2, fcw2, hpart, CHUNK);
            reduce_bn2<<<(CHUNK * 416 + 255) / 256, 256, 0, stream>>>(
                hpart, CHUNK, NZ, fc_b, bn2_g, bn2_b, bn2_m, bn2_v, xob, cb);
        }
    }

    // logits = x1 @ x2^T + b_bias[col]  -> f32 (2048x2048)
    gemm_bt<4><<<dim3(16, 16), 256, 0, stream>>>(x1b, x2b, out, 2048, 2048, 416, 2048, bbias);
}

// Round 12
// 324.584 us; speedup vs baseline: 1.1912x; 1.1912x over previous
//
#include <hip/hip_runtime.h>
#include <hip/hip_bf16.h>
#include <stdint.h>

#define EPSF 1e-5f

typedef __attribute__((ext_vector_type(8))) short short8;
typedef __attribute__((ext_vector_type(4))) float f32x4;

__device__ inline short f2bf(float f) {
    union { float f; unsigned u; } x; x.f = f;
    unsigned u = x.u;
    unsigned r = (u + 0x7FFFu + ((u >> 16) & 1u)) >> 16;  // round-to-nearest-even
    return (short)r;
}

__device__ inline f32x4 mfma16x16x32(short8 a, short8 b, f32x4 c) {
    return __builtin_amdgcn_mfma_f32_16x16x32_bf16(a, b, c, 0, 0, 0);
}

// K-tile-major blocked layouts for the big fc GEMM. K = 96*392 = 37632 EXACT
// (1176 tiles of 32).  flat2[ks][b][32] (A)   fcw2[ks][d in 512][32] (B).
// 16B block jb stored at jb ^ ((row>>1)&3): bank swizzle baked into memory.

// ---------------------------------------------------------------------------
// fc GEMM (round-10 verified, + T1 XCD swizzle): C_part[z] = A2 * W2^T slice.
// Block 256x128, 4 waves (2x2), wave tile 128x64. A-only LDS, 4 slabs
// (64 KB), staged t+3 ahead. B in registers (double-buffered via 2-step
// unroll). One barrier per K-step; boundary ladder vmcnt(12/8/4/0).
// XCD swizzle: hw round-robins orig-id%8 across XCDs; remap so XCD k gets a
// CONTIGUOUS logical chunk -> same-z blocks (sharing the B K-slice ~2.3MB)
// land on one XCD's L2 instead of bouncing through L3. Bijective (nwg%8==0).
// ---------------------------------------------------------------------------
__global__ __launch_bounds__(256, 2) void gemm_fck(
    const short* __restrict__ A2, const short* __restrict__ W2,
    float* __restrict__ C, int CHUNK)
{
    __shared__ alignas(16) short As[4][256 * 32];

    const int tid = threadIdx.x;
    const int l   = tid & 63;
    const int w   = tid >> 6;

    // --- T1 XCD-aware block remap ---
    int bx = blockIdx.x, by = blockIdx.y, bz = blockIdx.z;
    {
        const int nwg = gridDim.x * gridDim.y * gridDim.z;
        if ((nwg & 7) == 0) {
            int orig = blockIdx.x + gridDim.x * (blockIdx.y + gridDim.y * blockIdx.z);
            int logical = (orig & 7) * (nwg >> 3) + (orig >> 3);
            bx = logical % gridDim.x;
            int rest = logical / gridDim.x;
            by = rest % gridDim.y;
            bz = rest / gridDim.y;
        }
    }

    const int wr  = w >> 1, wc = w & 1;
    const int m0  = bx * 256;
    const int nb  = by * 128;

    const int TILES = 1176;
    long long z = bz;
    const int s0 = (int)(z * TILES / gridDim.z);
    const int s1 = (int)((z + 1) * TILES / gridDim.z);
    const int nt = s1 - s0;

    const int lr   = l & 15;
    const int kg   = l >> 4;
    const int kswz = (kg ^ ((lr >> 1) & 3)) * 8;

    const size_t ASTEP = (size_t)CHUNK * 32;
    const size_t BSTEP = 512 * 32;
    const short* aB = A2 + (size_t)s0 * ASTEP + (size_t)m0 * 32 + w * 2048 + l * 8;
    const short* bP[4];
#pragma unroll
    for (int ni = 0; ni < 4; ++ni) {
        int r = nb + wc * 64 + ni * 16 + lr;
        bP[ni] = W2 + (size_t)s0 * BSTEP + (size_t)r * 32 + kswz;
    }

    auto stageA = [&](int buf, int tk) {
        const short* p = aB + (size_t)tk * ASTEP;
#pragma unroll
        for (int i = 0; i < 4; ++i)
            __builtin_amdgcn_global_load_lds(
                (const __attribute__((address_space(1))) void*)(p + i * 512),
                (__attribute__((address_space(3))) void*)(&As[buf][(w * 4 + i) * 512]), 16, 0, 0);
    };

    f32x4 acc[8][4] = {};
    int rd = 0;

    short8 bfC0, bfC1, bfC2, bfC3, bfN0, bfN1, bfN2, bfN3;

    stageA(0, 0);
    if (nt > 1) stageA(1, 1);
    if (nt > 2) stageA(2, 2);
    bfC0 = *(const short8*)(bP[0]); bfC1 = *(const short8*)(bP[1]);
    bfC2 = *(const short8*)(bP[2]); bfC3 = *(const short8*)(bP[3]);
    if (nt > 2)      { asm volatile("s_waitcnt vmcnt(12)" ::: "memory"); }
    else if (nt > 1) { asm volatile("s_waitcnt vmcnt(8)"  ::: "memory"); }
    else             { asm volatile("s_waitcnt vmcnt(4)"  ::: "memory"); }
    __builtin_amdgcn_s_barrier();
    __builtin_amdgcn_sched_barrier(0);

    auto kstep = [&](int t, const short8& u0, const short8& u1,
                     const short8& u2, const short8& u3,
                     short8& v0, short8& v1, short8& v2, short8& v3) {
        int wb = rd + 3; if (wb >= 4) wb -= 4;
        if (t + 1 < nt) {
            const size_t bo = (size_t)(t + 1) * BSTEP;
            v0 = *(const short8*)(bP[0] + bo);
            v1 = *(const short8*)(bP[1] + bo);
            v2 = *(const short8*)(bP[2] + bo);
            v3 = *(const short8*)(bP[3] + bo);
        }
        const short* Ar = &As[rd][0];
        short8 af[8];
#pragma unroll
        for (int mi = 0; mi < 8; ++mi)
            af[mi] = *(const short8*)&Ar[(wr * 128 + mi * 16 + lr) * 32 + kswz];
        if (t + 3 < nt) stageA(wb, t + 3);
        asm volatile("s_waitcnt lgkmcnt(0)" ::: "memory");
        __builtin_amdgcn_sched_barrier(0);
        __builtin_amdgcn_s_setprio(1);
#pragma unroll
        for (int mi = 0; mi < 8; ++mi) {
            acc[mi][0] = mfma16x16x32(af[mi], u0, acc[mi][0]);
            acc[mi][1] = mfma16x16x32(af[mi], u1, acc[mi][1]);
            acc[mi][2] = mfma16x16x32(af[mi], u2, acc[mi][2]);
            acc[mi][3] = mfma16x16x32(af[mi], u3, acc[mi][3]);
        }
        __builtin_amdgcn_s_setprio(0);
        __builtin_amdgcn_sched_barrier(0);
        if (t + 3 < nt)      { asm volatile("s_waitcnt vmcnt(12)" ::: "memory"); }
        else if (t + 2 < nt) { asm volatile("s_waitcnt vmcnt(8)"  ::: "memory"); }
        else if (t + 1 < nt) { asm volatile("s_waitcnt vmcnt(4)"  ::: "memory"); }
        else                 { asm volatile("s_waitcnt vmcnt(0)"  ::: "memory"); }
        __builtin_amdgcn_s_barrier();
        __builtin_amdgcn_sched_barrier(0);
        if (++rd == 4) rd = 0;
    };

    int t = 0;
    for (; t + 2 <= nt; t += 2) {
        kstep(t,     bfC0, bfC1, bfC2, bfC3, bfN0, bfN1, bfN2, bfN3);
        kstep(t + 1, bfN0, bfN1, bfN2, bfN3, bfC0, bfC1, bfC2, bfC3);
    }
    if (t < nt)
        kstep(t, bfC0, bfC1, bfC2, bfC3, bfN0, bfN1, bfN2, bfN3);

    float* Cb = C + (size_t)bz * CHUNK * 400;
#pragma unroll
    for (int ni = 0; ni < 4; ++ni) {
        int col = nb + wc * 64 + ni * 16 + lr;
        if (col >= 400) continue;
#pragma unroll
        for (int mi = 0; mi < 8; ++mi) {
            int row0 = m0 + wr * 128 + mi * 16 + kg * 4;
#pragma unroll
            for (int r = 0; r < 4; ++r)
                Cb[(size_t)(row0 + r) * 400 + col] = acc[mi][ni][r];
        }
    }
}

// ---------------------------------------------------------------------------
// BT-GEMM template (round-7 structure, verified at MF=8): row-major A[M,KP],
// B[N,KP], full-K + bias. Block (MF*32) x 128. MF=2: 64x128 block, 36 KB
// LDS, small acc -> high block count for short-K GEMMs (fc1, logits).
// Boundary wait keeps exactly one stage batch (MF/2+2 ops) in flight.
// ---------------------------------------------------------------------------
template <int MF>
__global__ __launch_bounds__(256, 2) void gemm_bt(
    const short* __restrict__ A, const short* __restrict__ B,
    float* __restrict__ C, int M, int N, int KP, int ldc,
    const float* __restrict__ bias)
{
    constexpr int RM = MF * 32;
    constexpr int HG = MF / 2;
    __shared__ alignas(16) short As[3][RM * 32];
    __shared__ alignas(16) short Bs[3][128 * 32];

    const int tid = threadIdx.x;
    const int l   = tid & 63;
    const int w   = tid >> 6;
    const int wr  = w >> 1, wc = w & 1;
    const int m0  = blockIdx.x * RM;
    const int n0  = blockIdx.y * 128;

    const int sr   = l >> 2;
    const int sc   = ((l & 3) ^ ((sr >> 1) & 3)) * 8;
    const int lr   = l & 15;
    const int kg   = l >> 4;
    const int kswz = (kg ^ ((lr >> 1) & 3)) * 8;

    const short* gaB[HG];
#pragma unroll
    for (int i = 0; i < HG; ++i)
        gaB[i] = A + (size_t)(m0 + (w * HG + i) * 16 + sr) * KP + sc;
    const short* gbB[2];
#pragma unroll
    for (int i = 0; i < 2; ++i) {
        int rB = n0 + (w * 2 + i) * 16 + sr;
        if (rB > N - 1) rB = N - 1;
        gbB[i] = B + (size_t)rB * KP + sc;
    }

    auto stageA = [&](int buf, int k0) {
#pragma unroll
        for (int i = 0; i < HG; ++i)
            __builtin_amdgcn_global_load_lds(
                (const __attribute__((address_space(1))) void*)(gaB[i] + k0),
                (__attribute__((address_space(3))) void*)(&As[buf][(w * HG + i) * 512]), 16, 0, 0);
    };
    auto stageB = [&](int buf, int k0) {
#pragma unroll
        for (int i = 0; i < 2; ++i)
            __builtin_amdgcn_global_load_lds(
                (const __attribute__((address_space(1))) void*)(gbB[i] + k0),
                (__attribute__((address_space(3))) void*)(&Bs[buf][(w * 2 + i) * 512]), 16, 0, 0);
    };
    auto wait_batch = [&]() {   // keep one stage batch (HG+2 ops) in flight
        if constexpr (MF == 8)      { asm volatile("s_waitcnt vmcnt(6)" ::: "memory"); }
        else if constexpr (MF == 4) { asm volatile("s_waitcnt vmcnt(4)" ::: "memory"); }
        else                        { asm volatile("s_waitcnt vmcnt(3)" ::: "memory"); }
    };

    f32x4 acc[MF][4] = {};

    const int nt = KP >> 5;
    stageA(0, 0); stageB(0, 0);
    if (nt > 1) { stageA(1, 32); stageB(1, 32); }
    if (nt > 1) { wait_batch(); }
    else        { asm volatile("s_waitcnt vmcnt(0)" ::: "memory"); }
    __builtin_amdgcn_s_barrier();
    __builtin_amdgcn_sched_barrier(0);

    int rd = 0;
    for (int t = 0; t < nt; ++t) {
        int wb = rd + 2; if (wb >= 3) wb -= 3;
        const int kpre = (t + 2) << 5;
        const short* Ar = &As[rd][0];
        const short* Br = &Bs[rd][0];
        short8 af[HG], bf[4], af2[HG];

#pragma unroll
        for (int mi = 0; mi < HG; ++mi)
            af[mi] = *(const short8*)&Ar[(wr * (MF * 16) + mi * 16 + lr) * 32 + kswz];
#pragma unroll
        for (int ni = 0; ni < 4; ++ni)
            bf[ni] = *(const short8*)&Br[(wc * 64 + ni * 16 + lr) * 32 + kswz];
        if (t + 2 < nt) stageA(wb, kpre);
        __builtin_amdgcn_s_barrier();
        asm volatile("s_waitcnt lgkmcnt(0)" ::: "memory");
        __builtin_amdgcn_sched_barrier(0);
        __builtin_amdgcn_s_setprio(1);
#pragma unroll
        for (int mi = 0; mi < HG; ++mi)
#pragma unroll
            for (int ni = 0; ni < 4; ++ni)
                acc[mi][ni] = mfma16x16x32(af[mi], bf[ni], acc[mi][ni]);
        __builtin_amdgcn_s_setprio(0);
        __builtin_amdgcn_sched_barrier(0);
        __builtin_amdgcn_s_barrier();
        __builtin_amdgcn_sched_barrier(0);

#pragma unroll
        for (int mi = 0; mi < HG; ++mi)
            af2[mi] = *(const short8*)&Ar[(wr * (MF * 16) + (mi + HG) * 16 + lr) * 32 + kswz];
        if (t + 2 < nt) stageB(wb, kpre);
        __builtin_amdgcn_s_barrier();
        asm volatile("s_waitcnt lgkmcnt(0)" ::: "memory");
        __builtin_amdgcn_sched_barrier(0);
        __builtin_amdgcn_s_setprio(1);
#pragma unroll
        for (int mi = 0; mi < HG; ++mi)
#pragma unroll
            for (int ni = 0; ni < 4; ++ni)
                acc[mi + HG][ni] = mfma16x16x32(af2[mi], bf[ni], acc[mi + HG][ni]);
        __builtin_amdgcn_s_setprio(0);
        __builtin_amdgcn_sched_barrier(0);
        if (t + 2 < nt) { wait_batch(); }
        else            { asm volatile("s_waitcnt vmcnt(0)" ::: "memory"); }
        __builtin_amdgcn_s_barrier();
        __builtin_amdgcn_sched_barrier(0);

        if (++rd == 3) rd = 0;
    }

#pragma unroll
    for (int ni = 0; ni < 4; ++ni) {
        int col = n0 + wc * 64 + ni * 16 + lr;
        if (col >= N) continue;
        float bv = bias ? bias[col] : 0.0f;
#pragma unroll
        for (int mi = 0; mi < MF; ++mi) {
            int row0 = m0 + wr * (MF * 16) + mi * 16 + kg * 4;
#pragma unroll
            for (int r = 0; r < 4; ++r)
                C[(size_t)(row0 + r) * ldc + col] = acc[mi][ni][r] + bv;
        }
    }
}

// ---------------------------------------------------------------------------
// fused gathers: entity row + BN0 -> f32 x[2048,400]; relation row -> bf16
// padded to 416 cols
// ---------------------------------------------------------------------------
__global__ void gather_fused(const float* __restrict__ E, const int* __restrict__ eidx,
                             const float* __restrict__ R, const int* __restrict__ ridx,
                             const float* g, const float* bb, const float* m,
                             const float* v, float* __restrict__ xout,
                             short* __restrict__ rout)
{
    int b = blockIdx.x;
    int e = eidx[b];
    float s = g[0] * rsqrtf(v[0] + EPSF);
    float t = bb[0] - m[0] * s;
    const float4* src = (const float4*)(E + (size_t)e * 400);
    float4* dst = (float4*)(xout + (size_t)b * 400);
    for (int i = threadIdx.x; i < 100; i += blockDim.x) {
        float4 u = src[i];
        dst[i] = make_float4(u.x * s + t, u.y * s + t, u.z * s + t, u.w * s + t);
    }
    int r = ridx[b];
    const float* rsrc = R + (size_t)r * 400;
    short* rdst = rout + (size_t)b * 416;
    for (int i = threadIdx.x; i < 416; i += blockDim.x)
        rdst[i] = (i < 400) ? f2bf(rsrc[i]) : (short)0;
}

// fc_w (400 x 37632) f32 -> blocked/swizzled fcw2[ks][512][32] bf16.
__global__ void cvt_fcw2(const float* __restrict__ fc_w, short* __restrict__ fcw2)
{
    int i = blockIdx.x * blockDim.x + threadIdx.x;
    if (i >= 1176 * 512 * 4) return;
    int p  = i & 3;
    int d  = (i >> 2) & 511;
    int ks = i >> 11;
    int jb = p ^ ((d >> 1) & 3);
    int c0 = ks * 32 + jb * 8;
    unsigned o = (unsigned)c0 / 392u;
    int lc = c0 - (int)o * 392;
    short8 v = {};
    if (d < 400) {
        const float* src = fc_w + (size_t)d * 37632 + o * 392 + lc;
#pragma unroll
        for (int j = 0; j < 8; ++j) v[j] = f2bf(src[j]);
    }
    *(short8*)(fcw2 + (size_t)i * 8) = v;
}

// fc1_w (864 x 400) f32 -> bf16 padded to ld 416
__global__ void cvt_fc1w_pad(const float* __restrict__ in, short* __restrict__ out)
{
    int i = blockIdx.x * blockDim.x + threadIdx.x;
    if (i >= 864 * 416) return;
    int row = i / 416, col = i - row * 416;
    out[i] = (col < 400) ? f2bf(in[row * 400 + col]) : (short)0;
}

// ---------------------------------------------------------------------------
// conv + BN1 -> blocked/swizzled flat2[ks][rc][32] bf16 (round-10 verified).
// ---------------------------------------------------------------------------
__global__ __launch_bounds__(256, 3) void conv_blk(
    const float* __restrict__ xall, const float* __restrict__ kfall,
    const float* __restrict__ g1, const float* __restrict__ b1,
    const float* __restrict__ m1, const float* __restrict__ v1,
    short* __restrict__ flat2, int CHUNK, int cb)
{
    __shared__ float xs[8][401];
    __shared__ float kfs[8][866];
    __shared__ float s1s[96], t1s[96];

    const int tid = threadIdx.x;
    const int b0  = blockIdx.x * 8;
    const int ts0 = blockIdx.y * 588;
    const int ts1 = ts0 + 588;

    for (int i = tid; i < 800; i += 256) {
        int row = i / 100, q = i - row * 100;
        float4 u = ((const float4*)(xall + (size_t)(cb + b0 + row) * 400))[q];
        xs[row][q * 4 + 0] = u.x; xs[row][q * 4 + 1] = u.y;
        xs[row][q * 4 + 2] = u.z; xs[row][q * 4 + 3] = u.w;
    }
    for (int i = tid; i < 1728; i += 256) {
        int row = i / 216, q = i - row * 216;
        float4 u = ((const float4*)(kfall + (size_t)(cb + b0 + row) * 864))[q];
        kfs[row][q * 4 + 0] = u.x; kfs[row][q * 4 + 1] = u.y;
        kfs[row][q * 4 + 2] = u.z; kfs[row][q * 4 + 3] = u.w;
    }
    if (tid < 96) {
        float s = g1[tid] * rsqrtf(v1[tid] + EPSF);
        s1s[tid] = s;
        t1s[tid] = b1[tid] - m1[tid] * s;
    }
    __syncthreads();

    const int l  = tid & 63;
    const int w  = tid >> 6;
    const int th = l >> 5;
    const int sl = (l >> 2) & 7;
    const int p  = l & 3;
    const int rc = b0 + sl;
    const int jb = p ^ ((rc >> 1) & 3);

    const float* xr = &xs[sl][0];
    const float* kr = &kfs[sl][0];
    short* outb = flat2 + (size_t)rc * 32 + p * 8;

    for (int ks = ts0 + w * 2 + th; ks < ts1; ks += 8) {
        int c0 = ks * 32 + jb * 8;
        unsigned o = (unsigned)c0 / 392u;
        int l0 = c0 - (int)o * 392;
        float k9[9];
#pragma unroll
        for (int f = 0; f < 9; ++f) k9[f] = kr[o * 9 + f];
        float s1 = s1s[o], t1 = t1s[o];
        float xv[16];
#pragma unroll
        for (int j = 0; j < 16; ++j) xv[j] = xr[l0 + j];
        short8 v;
#pragma unroll
        for (int j = 0; j < 8; ++j) {
            float a = 0.f;
#pragma unroll
            for (int f = 0; f < 9; ++f) a += xv[j + f] * k9[f];
            v[j] = f2bf(a * s1 + t1);
        }
        *(short8*)(outb + (size_t)ks * CHUNK * 32) = v;
    }
}

// ---------------------------------------------------------------------------
// sum NZ split-K partials + fc_b + BN2 + ReLU -> bf16, 4 cols/thread via
// float4 loads / short4 stores. i covers C*104 quads (100 data + 4 pad).
// ---------------------------------------------------------------------------
__global__ void reduce_bn2(const float* __restrict__ hp, int C, int nz,
                           const float* __restrict__ fcb,
                           const float* __restrict__ g2, const float* __restrict__ b2,
                           const float* __restrict__ m2, const float* __restrict__ v2,
                           short* __restrict__ xout, int cb)
{
    int i = blockIdx.x * blockDim.x + threadIdx.x;
    if (i >= C * 104) return;
    int row = i / 104, j = i - row * 104;
    short4 val = make_short4(0, 0, 0, 0);
    int col = j * 4;
    if (j < 100) {
        float4 s = make_float4(0.f, 0.f, 0.f, 0.f);
        size_t stride = (size_t)C * 400;
        const float* base = hp + (size_t)row * 400 + col;
        for (int k = 0; k < nz; ++k) {
            float4 u = *(const float4*)(base + k * stride);
            s.x += u.x; s.y += u.y; s.z += u.z; s.w += u.w;
        }
        float o[4] = {s.x, s.y, s.z, s.w};
        short r[4];
#pragma unroll
        for (int q = 0; q < 4; ++q) {
            int c = col + q;
            float sc = g2[c] * rsqrtf(v2[c] + EPSF);
            float hv = (o[q] + fcb[c] - m2[c]) * sc + b2[c];
            r[q] = f2bf(fmaxf(hv, 0.f));
        }
        val = make_short4(r[0], r[1], r[2], r[3]);
    }
    *(short4*)(xout + (size_t)(cb + row) * 416 + col) = val;
}

extern "C" void kernel_launch(void* const* d_in, const int* in_sizes, int n_in,
                              void* d_out, int out_size, void* d_ws, size_t ws_size,
                              hipStream_t stream)
{
    (void)in_sizes; (void)n_in; (void)out_size;
    const int*   e1    = (const int*)d_in[0];
    const int*   r1i   = (const int*)d_in[1];
    const int*   r2i   = (const int*)d_in[2];
    const int*   e2    = (const int*)d_in[3];
    const float* E_w   = (const float*)d_in[4];
    const float* R_w   = (const float*)d_in[5];
    const float* fc1_w = (const float*)d_in[6];
    const float* fc1_b = (const float*)d_in[7];
    const float* fc_w  = (const float*)d_in[8];
    const float* fc_b  = (const float*)d_in[9];
    const float* bn0_g = (const float*)d_in[10];
    const float* bn0_b = (const float*)d_in[11];
    const float* bn0_m = (const float*)d_in[12];
    const float* bn0_v = (const float*)d_in[13];
    const float* bn1_g = (const float*)d_in[14];
    const float* bn1_b = (const float*)d_in[15];
    const float* bn1_m = (const float*)d_in[16];
    const float* bn1_v = (const float*)d_in[17];
    const float* bn2_g = (const float*)d_in[18];
    const float* bn2_b = (const float*)d_in[19];
    const float* bn2_m = (const float*)d_in[20];
    const float* bn2_v = (const float*)d_in[21];
    const float* bbias = (const float*)d_in[22];
    float* out = (float*)d_out;

    char* basep = (char*)d_ws;
    size_t off = 0;
    auto alloc = [&](size_t bytes) -> char* {
        char* p = basep + off;
        off = (off + bytes + 255) & ~(size_t)255;
        return p;
    };
    short* fcw2   = (short*)alloc(1176ULL * 512 * 32 * 2);
    short* fc1w_b = (short*)alloc(864ULL * 416 * 2);
    float* xf     = (float*)alloc(2048ULL * 400 * 4);
    short* rb     = (short*)alloc(2048ULL * 416 * 2);
    float* kf     = (float*)alloc(2048ULL * 864 * 4);
    short* x1b    = (short*)alloc(2048ULL * 416 * 2);
    short* x2b    = (short*)alloc(2048ULL * 416 * 2);
    size_t fixed = off;

    const int NZ = 16;   // split-K ways: grid 8x4x16 = 512 = 2 blocks/CU
    int CHUNK = 256;
    for (int c = 2048; c >= 256; c >>= 1) {
        size_t need = fixed + ((size_t)c * 400 * NZ * 4 + 256)
                            + ((size_t)c * 37632 * 2 + 256);
        if (need <= ws_size) { CHUNK = c; break; }
    }
    float* hpart = (float*)alloc((size_t)CHUNK * 400 * NZ * 4);
    short* flat2 = (short*)alloc((size_t)CHUNK * 37632 * 2);

    cvt_fcw2<<<(1176 * 512 * 4 + 255) / 256, 256, 0, stream>>>(fc_w, fcw2);
    cvt_fc1w_pad<<<(864 * 416 + 255) / 256, 256, 0, stream>>>(fc1_w, fc1w_b);

    for (int br = 0; br < 2; ++br) {
        const int* eidx = (br == 0) ? e1 : e2;
        const int* ridx = (br == 0) ? r1i : r2i;
        short* xob = (br == 0) ? x1b : x2b;

        gather_fused<<<2048, 128, 0, stream>>>(E_w, eidx, R_w, ridx,
                                               bn0_g, bn0_b, bn0_m, bn0_v, xf, rb);
        // k filters: (2048x400) @ (864x400)^T + fc1_b -> f32 (2048x864)
        gemm_bt<2><<<dim3(32, 7), 256, 0, stream>>>(rb, fc1w_b, kf, 2048, 864, 416, 864, fc1_b);

        for (int cb = 0; cb < 2048; cb += CHUNK) {
            conv_blk<<<dim3(CHUNK / 8, 2), 256, 0, stream>>>(
                xf, kf, bn1_g, bn1_b, bn1_m, bn1_v, flat2, CHUNK, cb);
            gemm_fck<<<dim3(CHUNK / 256, 4, NZ), 256, 0, stream>>>(
                flat2, fcw2, hpart, CHUNK);
            reduce_bn2<<<(CHUNK * 104 + 255) / 256, 256, 0, stream>>>(
                hpart, CHUNK, NZ, fc_b, bn2_g, bn2_b, bn2_m, bn2_v, xob, cb);
        }
    }

    // logits = x1 @ x2^T + b_bias[col]  -> f32 (2048x2048)
    gemm_bt<2><<<dim3(32, 16), 256, 0, stream>>>(x1b, x2b, out, 2048, 2048, 416, 2048, bbias);
}